// Round 1
// 1986.007 us; speedup vs baseline: 1.0055x; 1.0055x over previous
//
#include <hip/hip_runtime.h>
#include <hip/hip_bf16.h>

#define H2 2048     // student hidden
#define HT 4096     // teacher hidden
#define NV 32000    // vocab
#define NBT 2048    // batch*time rows

// primary (pipelined) tile
#define BM2 128
#define BN2 256
#define BK2 64
#define NVB2 (NV / BN2)   // 125

// fallback tile (round-1 kernel)
#define BM 128
#define BN 128
#define BK 32
#define LDT 40
#define NVB (NV / BN)     // 250

typedef __attribute__((ext_vector_type(8))) short short8;
typedef __attribute__((ext_vector_type(8))) unsigned short ushort8;
typedef __attribute__((ext_vector_type(4))) float floatx4;

static __device__ __forceinline__ unsigned int pk_bf16(float a, float b) {
  __hip_bfloat162 h = __float22bfloat162_rn(make_float2(a, b));
  union { __hip_bfloat162 h; unsigned int u; } c;
  c.h = h;
  return c.u;
}

// direct global->LDS DMA, 16 B per lane
static __device__ __forceinline__ void gload_lds16(const void* g, void* l) {
  __builtin_amdgcn_global_load_lds(
      (const __attribute__((address_space(1))) unsigned int*)g,
      (__attribute__((address_space(3))) unsigned int*)l, 16, 0, 0);
}

// fp32 -> bf16 (bits) conversion, 8 elems/thread
__global__ void cvt_bf16_kernel(const float* __restrict__ src,
                                unsigned int* __restrict__ dst, int n) {
  int i = blockIdx.x * blockDim.x + threadIdx.x;
  int base = i * 8;
  if (base >= n) return;
  float4 f0 = *(const float4*)(src + base);
  float4 f1 = *(const float4*)(src + base + 4);
  uint4 o;
  o.x = pk_bf16(f0.x, f0.y);
  o.y = pk_bf16(f0.z, f0.w);
  o.z = pk_bf16(f1.x, f1.y);
  o.w = pk_bf16(f1.z, f1.w);
  *(uint4*)(dst + i * 4) = o;
}

// ---------------------------------------------------------------------------
// Primary path: 128x256x64 tile, 8 waves, double-buffered LDS with counted
// vmcnt pipeline (T3/T4), XOR-swizzled conflict-free ds_read_b128 (T2, via
// pre-swizzled global source since global_load_lds writes linearly), setprio
// around the MFMA cluster (T5), XCD-chunked block swizzle (T1).
//
// LDS data layout: row-major [rows][BK2] bf16, but 16B-unit u of row r holds
// global k-chunk (u ^ (r&7)).  Readers apply the same XOR.  Staging flat
// index f = issue*512 + tid -> LDS row f>>3, unit f&7; the global source for
// that slot is row (f>>3), k-chunk ((f&7) ^ ((f>>3)&7)).
// ---------------------------------------------------------------------------

template <int K>
static __device__ __forceinline__ void gemm_pipe(
    const unsigned short* __restrict__ act,   // [.][K] bf16 bits
    const unsigned short* __restrict__ w,     // [.][K] bf16 bits
    const int row0, const int col0, const int tid,
    const int aoff, const int boff,
    unsigned short (*__restrict__ sA)[BM2 * BK2],   // [2][8192]
    unsigned short (*__restrict__ sB)[BN2 * BK2],   // [2][16384]
    floatx4 (&acc)[4][4])
{
  constexpr int NT = K / BK2;
  const int r8 = tid >> 3;                      // staging row within 64-row slab
  const int usw = ((tid & 7) ^ (r8 & 7)) * 8;   // pre-swizzled k-chunk (elems)

  const unsigned short* pa0 = act + (size_t)(row0 + r8) * K + usw;
  const unsigned short* pa1 = pa0 + (size_t)64 * K;
  const unsigned short* pb0 = w + (size_t)(col0 + r8) * K + usw;
  const unsigned short* pb1 = pb0 + (size_t)64 * K;
  const unsigned short* pb2 = pb0 + (size_t)128 * K;
  const unsigned short* pb3 = pb0 + (size_t)192 * K;

#define STAGE6(buf)                                   \
  do {                                                \
    gload_lds16(pa0, &sA[buf][tid * 8]);              \
    gload_lds16(pa1, &sA[buf][4096 + tid * 8]);       \
    gload_lds16(pb0, &sB[buf][tid * 8]);              \
    gload_lds16(pb1, &sB[buf][4096 + tid * 8]);       \
    gload_lds16(pb2, &sB[buf][8192 + tid * 8]);       \
    gload_lds16(pb3, &sB[buf][12288 + tid * 8]);      \
    pa0 += BK2; pa1 += BK2;                           \
    pb0 += BK2; pb1 += BK2; pb2 += BK2; pb3 += BK2;   \
  } while (0)

  // prologue: tiles 0 and 1 in flight; wait only for tile 0
  STAGE6(0);
  STAGE6(1);
  asm volatile("s_waitcnt vmcnt(6)" ::: "memory");
  __builtin_amdgcn_s_barrier();

#pragma unroll 1
  for (int t = 0; t < NT; ++t) {
    const int cur = t & 1;
    const unsigned short* sAc = sA[cur];
    const unsigned short* sBc = sB[cur];

    // 16 swizzled ds_read_b128 (conflict-minimal: 16 rows spread 8 slots)
    short8 a0[4], a1[4], b0[4], b1[4];
#pragma unroll
    for (int i = 0; i < 4; ++i) {
      a0[i] = *(const short8*)(sAc + (aoff + i * 1024));
      a1[i] = *(const short8*)(sAc + ((aoff ^ 32) + i * 1024));
    }
#pragma unroll
    for (int j = 0; j < 4; ++j) {
      b0[j] = *(const short8*)(sBc + (boff + j * 1024));
      b1[j] = *(const short8*)(sBc + ((boff ^ 32) + j * 1024));
    }
    // reads must land before any wave can overwrite buf[cur]
    asm volatile("s_waitcnt lgkmcnt(0)" ::: "memory");
    __builtin_amdgcn_s_barrier();               // A: buf[cur] consumed by all

    if (t + 2 < NT) {
      STAGE6(cur);                              // prefetch tile t+2 over cur
      asm volatile("s_waitcnt vmcnt(6)" ::: "memory");   // t+1 done; t+2 in flight
    } else if (t + 1 < NT) {
      asm volatile("s_waitcnt vmcnt(0)" ::: "memory");   // last prefetch done
    }
    __builtin_amdgcn_s_barrier();               // B: buf[cur^1] visible to all

    // MFMA cluster (reg-only) — overlaps next iter's ds_reads of other waves
    __builtin_amdgcn_s_setprio(1);
#pragma unroll
    for (int i = 0; i < 4; ++i)
#pragma unroll
      for (int j = 0; j < 4; ++j)
        acc[i][j] = __builtin_amdgcn_mfma_f32_16x16x32_bf16(
            a0[i], b0[j], acc[i][j], 0, 0, 0);
#pragma unroll
    for (int i = 0; i < 4; ++i)
#pragma unroll
      for (int j = 0; j < 4; ++j)
        acc[i][j] = __builtin_amdgcn_mfma_f32_16x16x32_bf16(
            a1[i], b1[j], acc[i][j], 0, 0, 0);
    __builtin_amdgcn_s_setprio(0);
  }
#undef STAGE6
}

__global__ __launch_bounds__(512, 2) void fused_gemm_pipe_kernel(
    const unsigned short* __restrict__ sbf,   // [NBT][H2] bf16
    const unsigned short* __restrict__ tbf,   // [NBT][HT] bf16
    const unsigned short* __restrict__ Wsb,   // [NV][H2] bf16
    const unsigned short* __restrict__ Wtb,   // [NV][HT] bf16
    const int* __restrict__ target,
    float* __restrict__ part,                 // [NVB2][4][NBT]
    float* __restrict__ s_tgt_out)            // [NBT]
{
  __shared__ unsigned short sA[2][BM2 * BK2];   // 32 KB
  __shared__ unsigned short sB[2][BN2 * BK2];   // 64 KB
  __shared__ float sRed[BM2][4];
  __shared__ int sTgt[BM2];

  const int tid = threadIdx.x;

  // XCD-chunked bijective swizzle: 2000 blocks, 2000 % 8 == 0.
  // XCD k gets contiguous tiles -> its 32 CUs share ~2 weight slabs in L2.
  const int lin = blockIdx.x + (int)gridDim.x * blockIdx.y;
  const int swz = (lin & 7) * 250 + (lin >> 3);
  const int bx = swz & 15;          // 16 row-blocks
  const int by = swz >> 4;          // 125 col-slabs
  const int row0 = bx * BM2;
  const int col0 = by * BN2;

  if (tid < BM2) {
    sTgt[tid] = target[row0 + tid];
    sRed[tid][0] = 0.f; sRed[tid][1] = 0.f;
    sRed[tid][2] = 0.f; sRed[tid][3] = 0.f;
  }

  const int lane = tid & 63;
  const int wv = tid >> 6;          // 8 waves: 2 row-groups x 4 col-groups
  const int wr = wv >> 2;
  const int wc = wv & 3;
  const int ku = lane >> 4;                       // k-chunk of this lane
  const int u0 = (ku ^ (lane & 7)) * 8;           // swizzled unit (elems)
  const int aoff = (wr * 64 + (lane & 15)) * BK2 + u0;
  const int boff = (wc * 64 + (lane & 15)) * BK2 + u0;

  floatx4 acc_s[4][4];
  floatx4 acc_t[4][4];
#pragma unroll
  for (int i = 0; i < 4; ++i)
#pragma unroll
    for (int j = 0; j < 4; ++j) {
      acc_s[i][j] = (floatx4){0.f, 0.f, 0.f, 0.f};
      acc_t[i][j] = (floatx4){0.f, 0.f, 0.f, 0.f};
    }

  gemm_pipe<H2>(sbf, Wsb, row0, col0, tid, aoff, boff, sA, sB, acc_s);
  gemm_pipe<HT>(tbf, Wtb, row0, col0, tid, aoff, boff, sA, sB, acc_t);

  // epilogue: per-row partials. C layout: col=lane&15, row=(lane>>4)*4+reg
#pragma unroll
  for (int i = 0; i < 4; ++i) {
#pragma unroll
    for (int r = 0; r < 4; ++r) {
      const int row_l = wr * 64 + i * 16 + (lane >> 4) * 4 + r;
      float e = 0.f, dp = 0.f, ss = 0.f, tt = 0.f;
#pragma unroll
      for (int j = 0; j < 4; ++j) {
        float s = acc_s[i][j][r];
        float t = acc_t[i][j][r];
        e += __expf(s);
        dp += s * t;
        ss += s * s;
        tt += t * t;
        const int col_l = wc * 64 + j * 16 + (lane & 15);
        if (sTgt[row_l] == col0 + col_l) s_tgt_out[row0 + row_l] = s;
      }
#pragma unroll
      for (int off = 1; off < 16; off <<= 1) {
        e  += __shfl_xor(e,  off, 16);
        dp += __shfl_xor(dp, off, 16);
        ss += __shfl_xor(ss, off, 16);
        tt += __shfl_xor(tt, off, 16);
      }
      if ((lane & 15) == 0) {
        atomicAdd(&sRed[row_l][0], e);
        atomicAdd(&sRed[row_l][1], dp);
        atomicAdd(&sRed[row_l][2], ss);
        atomicAdd(&sRed[row_l][3], tt);
      }
    }
  }
  __syncthreads();
  if (tid < BM2) {
    float* p = part + (size_t)by * 4 * NBT + row0 + tid;
    p[0]       = sRed[tid][0];
    p[NBT]     = sRed[tid][1];
    p[2 * NBT] = sRed[tid][2];
    p[3 * NBT] = sRed[tid][3];
  }
}

// ---------------------------------------------------------------------------
// Fallback path (round-1 kernel): fp32 weights, in-loop cvt — used only if
// ws_size can't hold the bf16 weight copies.
// ---------------------------------------------------------------------------

__global__ __launch_bounds__(256, 2) void fused_gemm_kernel(
    const unsigned short* __restrict__ sbf,
    const unsigned short* __restrict__ tbf,
    const float* __restrict__ Ws,
    const float* __restrict__ Wt,
    const int* __restrict__ target,
    float* __restrict__ part,
    float* __restrict__ s_tgt_out)
{
  __shared__ unsigned short sA[BM * LDT];
  __shared__ unsigned short sB[BN * LDT];
  __shared__ float sRed[BM][4];
  __shared__ int sTgt[BM];

  const int tid = threadIdx.x;
  const int row0 = blockIdx.x * BM;
  const int col0 = blockIdx.y * BN;
  const int lane = tid & 63;
  const int wv = tid >> 6;
  const int wr = wv >> 1;
  const int wc = wv & 1;

  if (tid < BM) {
    sTgt[tid] = target[row0 + tid];
    sRed[tid][0] = 0.f; sRed[tid][1] = 0.f;
    sRed[tid][2] = 0.f; sRed[tid][3] = 0.f;
  }

  floatx4 acc_s[4][4];
  floatx4 acc_t[4][4];
#pragma unroll
  for (int i = 0; i < 4; ++i)
#pragma unroll
    for (int j = 0; j < 4; ++j) {
      acc_s[i][j] = (floatx4){0.f, 0.f, 0.f, 0.f};
      acc_t[i][j] = (floatx4){0.f, 0.f, 0.f, 0.f};
    }

  const int sr = tid >> 1;
  const int sk = (tid & 1) << 4;
  const int mrow = lane & 15;
  const int koff = (lane >> 4) << 3;
  const int abase = (wr * 64 + mrow) * LDT + koff;
  const int bbase = (wc * 64 + mrow) * LDT + koff;

  {
    const unsigned short* ap = sbf + (size_t)(row0 + sr) * H2 + sk;
    const float* bp = Ws + (size_t)(col0 + sr) * H2 + sk;
#pragma unroll 1
    for (int k0 = 0; k0 < H2; k0 += BK) {
      ushort8 a0 = *(const ushort8*)(ap);
      ushort8 a1 = *(const ushort8*)(ap + 8);
      float4 b0 = *(const float4*)(bp);
      float4 b1 = *(const float4*)(bp + 4);
      float4 b2 = *(const float4*)(bp + 8);
      float4 b3 = *(const float4*)(bp + 12);
      ap += BK; bp += BK;
      __syncthreads();
      *(ushort8*)(&sA[sr * LDT + sk]) = a0;
      *(ushort8*)(&sA[sr * LDT + sk + 8]) = a1;
      uint4 u0, u1;
      u0.x = pk_bf16(b0.x, b0.y); u0.y = pk_bf16(b0.z, b0.w);
      u0.z = pk_bf16(b1.x, b1.y); u0.w = pk_bf16(b1.z, b1.w);
      u1.x = pk_bf16(b2.x, b2.y); u1.y = pk_bf16(b2.z, b2.w);
      u1.z = pk_bf16(b3.x, b3.y); u1.w = pk_bf16(b3.z, b3.w);
      *(uint4*)(&sB[sr * LDT + sk]) = u0;
      *(uint4*)(&sB[sr * LDT + sk + 8]) = u1;
      __syncthreads();
      short8 af[4], bfrag[4];
#pragma unroll
      for (int i = 0; i < 4; ++i)
        af[i] = *(const short8*)(&sA[abase + i * 16 * LDT]);
#pragma unroll
      for (int j = 0; j < 4; ++j)
        bfrag[j] = *(const short8*)(&sB[bbase + j * 16 * LDT]);
#pragma unroll
      for (int i = 0; i < 4; ++i)
#pragma unroll
        for (int j = 0; j < 4; ++j)
          acc_s[i][j] = __builtin_amdgcn_mfma_f32_16x16x32_bf16(
              af[i], bfrag[j], acc_s[i][j], 0, 0, 0);
    }
  }
  {
    const unsigned short* ap = tbf + (size_t)(row0 + sr) * HT + sk;
    const float* bp = Wt + (size_t)(col0 + sr) * HT + sk;
#pragma unroll 1
    for (int k0 = 0; k0 < HT; k0 += BK) {
      ushort8 a0 = *(const ushort8*)(ap);
      ushort8 a1 = *(const ushort8*)(ap + 8);
      float4 b0 = *(const float4*)(bp);
      float4 b1 = *(const float4*)(bp + 4);
      float4 b2 = *(const float4*)(bp + 8);
      float4 b3 = *(const float4*)(bp + 12);
      ap += BK; bp += BK;
      __syncthreads();
      *(ushort8*)(&sA[sr * LDT + sk]) = a0;
      *(ushort8*)(&sA[sr * LDT + sk + 8]) = a1;
      uint4 u0, u1;
      u0.x = pk_bf16(b0.x, b0.y); u0.y = pk_bf16(b0.z, b0.w);
      u0.z = pk_bf16(b1.x, b1.y); u0.w = pk_bf16(b1.z, b1.w);
      u1.x = pk_bf16(b2.x, b2.y); u1.y = pk_bf16(b2.z, b2.w);
      u1.z = pk_bf16(b3.x, b3.y); u1.w = pk_bf16(b3.z, b3.w);
      *(uint4*)(&sB[sr * LDT + sk]) = u0;
      *(uint4*)(&sB[sr * LDT + sk + 8]) = u1;
      __syncthreads();
      short8 af[4], bfrag[4];
#pragma unroll
      for (int i = 0; i < 4; ++i)
        af[i] = *(const short8*)(&sA[abase + i * 16 * LDT]);
#pragma unroll
      for (int j = 0; j < 4; ++j)
        bfrag[j] = *(const short8*)(&sB[bbase + j * 16 * LDT]);
#pragma unroll
      for (int i = 0; i < 4; ++i)
#pragma unroll
        for (int j = 0; j < 4; ++j)
          acc_t[i][j] = __builtin_amdgcn_mfma_f32_16x16x32_bf16(
              af[i], bfrag[j], acc_t[i][j], 0, 0, 0);
    }
  }

#pragma unroll
  for (int i = 0; i < 4; ++i) {
#pragma unroll
    for (int r = 0; r < 4; ++r) {
      const int row_l = wr * 64 + i * 16 + (lane >> 4) * 4 + r;
      float e = 0.f, dp = 0.f, ss = 0.f, tt = 0.f;
#pragma unroll
      for (int j = 0; j < 4; ++j) {
        float s = acc_s[i][j][r];
        float t = acc_t[i][j][r];
        e += __expf(s);
        dp += s * t;
        ss += s * s;
        tt += t * t;
        const int col_l = wc * 64 + j * 16 + (lane & 15);
        if (sTgt[row_l] == col0 + col_l) s_tgt_out[row0 + row_l] = s;
      }
#pragma unroll
      for (int off = 1; off < 16; off <<= 1) {
        e  += __shfl_xor(e,  off, 16);
        dp += __shfl_xor(dp, off, 16);
        ss += __shfl_xor(ss, off, 16);
        tt += __shfl_xor(tt, off, 16);
      }
      if ((lane & 15) == 0) {
        atomicAdd(&sRed[row_l][0], e);
        atomicAdd(&sRed[row_l][1], dp);
        atomicAdd(&sRed[row_l][2], ss);
        atomicAdd(&sRed[row_l][3], tt);
      }
    }
  }
  __syncthreads();
  if (tid < BM) {
    float* p = part + (size_t)blockIdx.y * 4 * NBT + row0 + tid;
    p[0]       = sRed[tid][0];
    p[NBT]     = sRed[tid][1];
    p[2 * NBT] = sRed[tid][2];
    p[3 * NBT] = sRed[tid][3];
  }
}

// ---------------------------------------------------------------------------

__global__ void row_loss_kernel(const float* __restrict__ part,
                                const float* __restrict__ s_tgt,
                                const int* __restrict__ target,
                                float* __restrict__ row_loss, int nvb) {
  const int row = blockIdx.x * blockDim.x + threadIdx.x;
  if (row >= NBT) return;
  float e = 0.f, dp = 0.f, ss = 0.f, tt = 0.f;
  for (int v = 0; v < nvb; ++v) {
    const float* p = part + (size_t)v * 4 * NBT + row;
    e  += p[0];
    dp += p[NBT];
    ss += p[2 * NBT];
    tt += p[3 * NBT];
  }
  const float lse = logf(e);
  const int tg = target[row];
  const float st = s_tgt[row];
  const float nll = (tg != -100) ? (lse - st) : 0.f;
  const float ns = fmaxf(sqrtf(ss), 1e-12f);
  const float nt = fmaxf(sqrtf(tt), 1e-12f);
  const float c = dp / (ns * nt);
  row_loss[row] = (0.5f * nll + 0.5f * (1.f - c)) * (1.f / (float)NBT);
}

__global__ void final_reduce_kernel(const float* __restrict__ row_loss,
                                    float* __restrict__ out) {
  __shared__ float sm[4];
  float v = 0.f;
  for (int i = threadIdx.x; i < NBT; i += 256) v += row_loss[i];
#pragma unroll
  for (int off = 32; off >= 1; off >>= 1) v += __shfl_down(v, off, 64);
  if ((threadIdx.x & 63) == 0) sm[threadIdx.x >> 6] = v;
  __syncthreads();
  if (threadIdx.x == 0) out[0] = sm[0] + sm[1] + sm[2] + sm[3];
}

extern "C" void kernel_launch(void* const* d_in, const int* in_sizes, int n_in,
                              void* d_out, int out_size, void* d_ws, size_t ws_size,
                              hipStream_t stream) {
  const float* student = (const float*)d_in[0];  // [2048][2048]
  const float* Ws      = (const float*)d_in[1];  // [32000][2048]
  const float* teacher = (const float*)d_in[2];  // [2048][4096]
  const float* Wt      = (const float*)d_in[3];  // [32000][4096]
  const int*   target  = (const int*)d_in[4];    // [2048]

  const size_t nS  = (size_t)NBT * H2;   //  4.19 M
  const size_t nT  = (size_t)NBT * HT;   //  8.39 M
  const size_t nWs = (size_t)NV * H2;    // 65.5 M
  const size_t nWt = (size_t)NV * HT;    // 131 M
  const size_t nPart2 = (size_t)NVB2 * 4 * NBT;
  const size_t nPart  = (size_t)NVB * 4 * NBT;

  const size_t ws_needed_big =
      (nS + nT + nWs + nWt) * 2 + (nPart2 + 2 * NBT) * 4;

  if (ws_size >= ws_needed_big) {
    // primary path: bf16 everything + pipelined 128x256x64 GEMM
    unsigned short* sbf = (unsigned short*)d_ws;
    unsigned short* tbf = sbf + nS;
    unsigned short* Wsb = tbf + nT;
    unsigned short* Wtb = Wsb + nWs;
    float* part     = (float*)(Wtb + nWt);
    float* s_tgt    = part + nPart2;
    float* row_loss = s_tgt + NBT;

    cvt_bf16_kernel<<<(int)(nS / 8 / 256), 256, 0, stream>>>(
        student, (unsigned int*)sbf, (int)nS);
    cvt_bf16_kernel<<<(int)(nT / 8 / 256), 256, 0, stream>>>(
        teacher, (unsigned int*)tbf, (int)nT);
    cvt_bf16_kernel<<<(int)(nWs / 8 / 256), 256, 0, stream>>>(
        Ws, (unsigned int*)Wsb, (int)nWs);
    cvt_bf16_kernel<<<(int)(nWt / 8 / 256), 256, 0, stream>>>(
        Wt, (unsigned int*)Wtb, (int)nWt);

    dim3 grid(NBT / BM2, NV / BN2);   // (16, 125)
    fused_gemm_pipe_kernel<<<grid, 512, 0, stream>>>(
        sbf, tbf, Wsb, Wtb, target, part, s_tgt);

    row_loss_kernel<<<NBT / 256, 256, 0, stream>>>(part, s_tgt, target,
                                                   row_loss, NVB2);
    final_reduce_kernel<<<1, 256, 0, stream>>>(row_loss, (float*)d_out);
  } else {
    // fallback: round-1 path (fp32 weights, in-loop cvt)
    unsigned short* sbf = (unsigned short*)d_ws;
    unsigned short* tbf = sbf + nS;
    float* part     = (float*)(tbf + nT);
    float* s_tgt    = part + nPart;
    float* row_loss = s_tgt + NBT;

    cvt_bf16_kernel<<<(int)(nS / 8 / 256), 256, 0, stream>>>(
        student, (unsigned int*)sbf, (int)nS);
    cvt_bf16_kernel<<<(int)(nT / 8 / 256), 256, 0, stream>>>(
        teacher, (unsigned int*)tbf, (int)nT);

    dim3 grid(NBT / BM, NV / BN);
    fused_gemm_kernel<<<grid, 256, 0, stream>>>(sbf, tbf, Ws, Wt, target,
                                                part, s_tgt);

    row_loss_kernel<<<NBT / 256, 256, 0, stream>>>(part, s_tgt, target,
                                                   row_loss, NVB);
    final_reduce_kernel<<<1, 256, 0, stream>>>(row_loss, (float*)d_out);
  }
}